// Round 4
// baseline (78.101 us; speedup 1.0000x reference)
//
#include <hip/hip_runtime.h>
#include <cstddef>
#include <cstdint>

#define D_MODEL 512
#define DK 64
#define LQ 1024
#define LK 1024
#define NB 2
#define LN_EPS 1e-6f
#define L2E2 2.8853900817779268f  // 2*log2(e)

// pack two floats to bf16x2 (RNE), low word = a
__device__ __forceinline__ uint32_t pack_bf2(float a, float b) {
  uint32_t ua = __float_as_uint(a), ub = __float_as_uint(b);
  ua = (ua + 0x7fffu + ((ua >> 16) & 1u)) >> 16;
  ub = (ub + 0x7fffu + ((ub >> 16) & 1u)) >> 16;
  return (ub << 16) | ua;
}

// ---------------- projections ----------------
// type 0: qp=q@Wq -> ab_g[row][d] = {v_d*e^{-2qp}, e^{-2qp}}  (A,B for scores)
// type 1: ek = e^{2*(k@Wk)}  (f32 row-major)   <-- exp FIXED this round
// type 2: vp = v@Wv
// Block: 256 thr, 16 rows, one projection type. W staged in LDS (stride 68:
// conflict-free b128 writes + b32 reads). Row values via wave-uniform s_loads.
#define PR_ROWS 16
#define PR_E 128
__global__ __launch_bounds__(256) void proj_kernel(
    const float* __restrict__ q, const float* __restrict__ k,
    const float* __restrict__ v, const float* __restrict__ Wq,
    const float* __restrict__ Wk, const float* __restrict__ Wv,
    const float* __restrict__ v_param, float2* __restrict__ ab_g,
    float* __restrict__ ek, float* __restrict__ vp) {
  __shared__ float wt[PR_E][68];
  const int tid = threadIdx.x;
  const int type = blockIdx.x >> 7;  // 128 row-groups per type
  const int r0 = (blockIdx.x & 127) * PR_ROWS;
  const float* __restrict__ in = (type == 0) ? q : (type == 1) ? k : v;
  const float* __restrict__ W = (type == 0) ? Wq : (type == 1) ? Wk : Wv;
  const int lane = tid & 63;
  const int wv = __builtin_amdgcn_readfirstlane(tid >> 6);
  const int rbase = r0 + wv * 4;
  const float* __restrict__ r0p = in + (size_t)(rbase + 0) * D_MODEL;
  const float* __restrict__ r1p = in + (size_t)(rbase + 1) * D_MODEL;
  const float* __restrict__ r2p = in + (size_t)(rbase + 2) * D_MODEL;
  const float* __restrict__ r3p = in + (size_t)(rbase + 3) * D_MODEL;
  float acc0 = 0.f, acc1 = 0.f, acc2 = 0.f, acc3 = 0.f;
  for (int et = 0; et < D_MODEL; et += PR_E) {
    __syncthreads();
#pragma unroll
    for (int t = 0; t < 8; ++t) {
      int i = tid + 256 * t;
      int e = i >> 4, c4 = (i & 15) * 4;
      *(float4*)&wt[e][c4] = *(const float4*)&W[(size_t)(et + e) * DK + c4];
    }
    __syncthreads();
#pragma unroll 8
    for (int e = 0; e < PR_E; ++e) {
      float wval = wt[e][lane];
      acc0 = fmaf(r0p[et + e], wval, acc0);
      acc1 = fmaf(r1p[et + e], wval, acc1);
      acc2 = fmaf(r2p[et + e], wval, acc2);
      acc3 = fmaf(r3p[et + e], wval, acc3);
    }
  }
  if (type == 0) {
    float vpar = v_param[lane];
    float i0 = __builtin_amdgcn_exp2f(-L2E2 * acc0);
    float i1 = __builtin_amdgcn_exp2f(-L2E2 * acc1);
    float i2 = __builtin_amdgcn_exp2f(-L2E2 * acc2);
    float i3 = __builtin_amdgcn_exp2f(-L2E2 * acc3);
    ab_g[(size_t)(rbase + 0) * DK + lane] = make_float2(vpar * i0, i0);
    ab_g[(size_t)(rbase + 1) * DK + lane] = make_float2(vpar * i1, i1);
    ab_g[(size_t)(rbase + 2) * DK + lane] = make_float2(vpar * i2, i2);
    ab_g[(size_t)(rbase + 3) * DK + lane] = make_float2(vpar * i3, i3);
  } else if (type == 1) {  // FIX: store e^{2*kp}, not raw kp
    ek[(size_t)(rbase + 0) * DK + lane] = __builtin_amdgcn_exp2f(L2E2 * acc0);
    ek[(size_t)(rbase + 1) * DK + lane] = __builtin_amdgcn_exp2f(L2E2 * acc1);
    ek[(size_t)(rbase + 2) * DK + lane] = __builtin_amdgcn_exp2f(L2E2 * acc2);
    ek[(size_t)(rbase + 3) * DK + lane] = __builtin_amdgcn_exp2f(L2E2 * acc3);
  } else {
    vp[(size_t)(rbase + 0) * DK + lane] = acc0;
    vp[(size_t)(rbase + 1) * DK + lane] = acc1;
    vp[(size_t)(rbase + 2) * DK + lane] = acc2;
    vp[(size_t)(rbase + 3) * DK + lane] = acc3;
  }
}

// ---------------- fused scores + softmax + PV + FC + LN ----------------
// 256 thr (4 waves), RB=4 rows/block, grid 512. K-tile TJ=256 stored as bf16
// pairs kt[32][258]: one ds_read_b32 per d-PAIR at immediate offset (zero
// address VALU, conflict-free). Per pair & row: pairwise-rcp additive score.
#define RB 4
#define TJ 256
#define NT (LK / TJ)
__global__ __launch_bounds__(256) void attn_kernel(
    const float2* __restrict__ ab_g, const float* __restrict__ ek,
    const float* __restrict__ vp, const float* __restrict__ resid,
    const float* __restrict__ Wfc, const float* __restrict__ gamma,
    const float* __restrict__ beta, float* __restrict__ out,
    float* __restrict__ attn_out) {
  __shared__ uint32_t kt[32 * 258];    // 33 KB bf16x2 pairs
  __shared__ float sc[RB][LK];         // 16 KB scores -> probs
  __shared__ float4 ab4s[RB][32];      // {A_2dp,B_2dp,A_2dp+1,B_2dp+1}
  __shared__ float4 pvred[4][RB][16];  // PV cross-wave partials
  __shared__ float ovl[RB][DK];        // attention output rows
  __shared__ float red[2][RB][4];      // LN reductions
  const int tid = threadIdx.x;
  const int row0 = blockIdx.x * RB;
  const int batch = row0 >> 10;
  const float* __restrict__ ek_b = ek + (size_t)batch * LK * DK;
  const float* __restrict__ vp_b = vp + (size_t)batch * LK * DK;

  float4 pf[16];
  {
    const float4* __restrict__ s4 = (const float4*)ek_b;
#pragma unroll
    for (int t = 0; t < 16; ++t) pf[t] = s4[tid + 256 * t];
  }
  {
    int r = tid >> 6, d = tid & 63;
    float2 abv = ab_g[(size_t)(row0 + r) * DK + d];
    ((float2*)&ab4s[r][d >> 1])[d & 1] = abv;
  }
#pragma unroll
  for (int t = 0; t < 16; ++t) {  // stage tile 0
    int i = tid + 256 * t;
    int j = i >> 4, dp0 = (i & 15) * 2;
    kt[dp0 * 258 + j] = pack_bf2(pf[t].x, pf[t].y);
    kt[(dp0 + 1) * 258 + j] = pack_bf2(pf[t].z, pf[t].w);
  }
  __syncthreads();

  const uint32_t* ktb = kt + tid;  // lane's j = tid
  for (int jt = 0; jt < NT; ++jt) {
    if (jt + 1 < NT) {  // prefetch next tile; hides under compute
      const float4* __restrict__ n4 =
          (const float4*)(ek_b + (size_t)(jt + 1) * TJ * DK);
#pragma unroll
      for (int t = 0; t < 16; ++t) pf[t] = n4[tid + 256 * t];
    }
    float a0 = 0.f, a1 = 0.f, a2 = 0.f, a3 = 0.f;
#pragma unroll
    for (int dp = 0; dp < 32; ++dp) {
      uint32_t kw = ktb[dp * 258];
      float klo = __uint_as_float(kw << 16);
      float khi = __uint_as_float(kw & 0xffff0000u);
      {
        float4 ab = ab4s[0][dp];
        float x1 = klo + ab.y, x2 = khi + ab.w;
        float num = fmaf(ab.z, x1, ab.x * x2);
        a0 = fmaf(num, __builtin_amdgcn_rcpf(x1 * x2), a0);
      }
      {
        float4 ab = ab4s[1][dp];
        float x1 = klo + ab.y, x2 = khi + ab.w;
        float num = fmaf(ab.z, x1, ab.x * x2);
        a1 = fmaf(num, __builtin_amdgcn_rcpf(x1 * x2), a1);
      }
      {
        float4 ab = ab4s[2][dp];
        float x1 = klo + ab.y, x2 = khi + ab.w;
        float num = fmaf(ab.z, x1, ab.x * x2);
        a2 = fmaf(num, __builtin_amdgcn_rcpf(x1 * x2), a2);
      }
      {
        float4 ab = ab4s[3][dp];
        float x1 = klo + ab.y, x2 = khi + ab.w;
        float num = fmaf(ab.z, x1, ab.x * x2);
        a3 = fmaf(num, __builtin_amdgcn_rcpf(x1 * x2), a3);
      }
    }
    int jg = jt * TJ + tid;
    sc[0][jg] = a0; sc[1][jg] = a1; sc[2][jg] = a2; sc[3][jg] = a3;
    __syncthreads();  // all kt reads done
    if (jt + 1 < NT) {
#pragma unroll
      for (int t = 0; t < 16; ++t) {
        int i = tid + 256 * t;
        int j = i >> 4, dp0 = (i & 15) * 2;
        kt[dp0 * 258 + j] = pack_bf2(pf[t].x, pf[t].y);
        kt[(dp0 + 1) * 258 + j] = pack_bf2(pf[t].z, pf[t].w);
      }
      __syncthreads();
    }
  }

  const int wvv = __builtin_amdgcn_readfirstlane(tid >> 6);
  const int lane = tid & 63;

  // softmax over score_j = C - 2*acc_j  ->  shift by min(acc); wave = row
  {
    const int r = wvv;
    float m = 1e30f;
#pragma unroll
    for (int i = 0; i < 16; ++i) m = fminf(m, sc[r][i * 64 + lane]);
#pragma unroll
    for (int off = 32; off > 0; off >>= 1) m = fminf(m, __shfl_xor(m, off));
    float p[16];
    float ssum = 0.f;
#pragma unroll
    for (int i = 0; i < 16; ++i) {
      float e = __builtin_amdgcn_exp2f((m - sc[r][i * 64 + lane]) * L2E2);
      p[i] = e;
      ssum += e;
    }
#pragma unroll
    for (int off = 32; off > 0; off >>= 1) ssum += __shfl_xor(ssum, off);
    float inv = __builtin_amdgcn_rcpf(ssum);
    float* __restrict__ arow = attn_out + (size_t)(row0 + r) * LK;
#pragma unroll
    for (int i = 0; i < 16; ++i) {
      float pn = p[i] * inv;
      sc[r][i * 64 + lane] = pn;  // keep for PV
      arow[i * 64 + lane] = pn;
    }
  }
  __syncthreads();

  // PV: wave owns 256-j slice; vp read once per block per j (serves 4 rows)
  {
    const int jj = lane >> 4, l16 = lane & 15;
    const float4* __restrict__ vp4 = (const float4*)vp_b;
    float4 a[RB];
#pragma unroll
    for (int r = 0; r < RB; ++r) a[r] = make_float4(0.f, 0.f, 0.f, 0.f);
#pragma unroll 4
    for (int it = 0; it < TJ / 4; ++it) {
      int j = (wvv << 8) + (it << 2) + jj;
      float4 vv = vp4[(size_t)j * (DK / 4) + l16];
#pragma unroll
      for (int r = 0; r < RB; ++r) {
        float pw = sc[r][j];
        a[r].x = fmaf(pw, vv.x, a[r].x);
        a[r].y = fmaf(pw, vv.y, a[r].y);
        a[r].z = fmaf(pw, vv.z, a[r].z);
        a[r].w = fmaf(pw, vv.w, a[r].w);
      }
    }
#pragma unroll
    for (int r = 0; r < RB; ++r) {
      a[r].x += __shfl_xor(a[r].x, 16); a[r].y += __shfl_xor(a[r].y, 16);
      a[r].z += __shfl_xor(a[r].z, 16); a[r].w += __shfl_xor(a[r].w, 16);
      a[r].x += __shfl_xor(a[r].x, 32); a[r].y += __shfl_xor(a[r].y, 32);
      a[r].z += __shfl_xor(a[r].z, 32); a[r].w += __shfl_xor(a[r].w, 32);
    }
    if (jj == 0) {
#pragma unroll
      for (int r = 0; r < RB; ++r) pvred[wvv][r][l16] = a[r];
    }
  }
  __syncthreads();
  if (tid < 64) {
    int r = tid >> 4, l16 = tid & 15;
    float4 s = make_float4(0.f, 0.f, 0.f, 0.f);
#pragma unroll
    for (int w = 0; w < 4; ++w) {
      float4 t = pvred[w][r][l16];
      s.x += t.x; s.y += t.y; s.z += t.z; s.w += t.w;
    }
    ((float4*)ovl[r])[l16] = s;
  }
  __syncthreads();

  // FC + residual + LayerNorm tail (rows stay in LDS)
  {
    const int c0 = tid, c1 = tid + 256;
    float y[RB][2];
#pragma unroll
    for (int r = 0; r < RB; ++r) {
      y[r][0] = resid[(size_t)(row0 + r) * D_MODEL + c0];
      y[r][1] = resid[(size_t)(row0 + r) * D_MODEL + c1];
    }
#pragma unroll 4
    for (int e = 0; e < DK; ++e) {
      float w0 = Wfc[(size_t)e * D_MODEL + c0];
      float w1 = Wfc[(size_t)e * D_MODEL + c1];
#pragma unroll
      for (int r = 0; r < RB; ++r) {
        float o = ovl[r][e];
        y[r][0] = fmaf(o, w0, y[r][0]);
        y[r][1] = fmaf(o, w1, y[r][1]);
      }
    }
#pragma unroll
    for (int r = 0; r < RB; ++r) {
      float s = y[r][0] + y[r][1];
#pragma unroll
      for (int off = 32; off > 0; off >>= 1) s += __shfl_xor(s, off);
      if (lane == 0) red[0][r][wvv] = s;
    }
    __syncthreads();
    float mu[RB];
#pragma unroll
    for (int r = 0; r < RB; ++r)
      mu[r] = (red[0][r][0] + red[0][r][1] + red[0][r][2] + red[0][r][3]) *
              (1.0f / D_MODEL);
#pragma unroll
    for (int r = 0; r < RB; ++r) {
      float d0 = y[r][0] - mu[r], d1 = y[r][1] - mu[r];
      float s = d0 * d0 + d1 * d1;
#pragma unroll
      for (int off = 32; off > 0; off >>= 1) s += __shfl_xor(s, off);
      if (lane == 0) red[1][r][wvv] = s;
    }
    __syncthreads();
    float g0 = gamma[c0], g1 = gamma[c1], b0 = beta[c0], b1 = beta[c1];
#pragma unroll
    for (int r = 0; r < RB; ++r) {
      float var = (red[1][r][0] + red[1][r][1] + red[1][r][2] + red[1][r][3]) *
                  (1.0f / D_MODEL);
      float rstd = rsqrtf(var + LN_EPS);
      out[(size_t)(row0 + r) * D_MODEL + c0] = (y[r][0] - mu[r]) * rstd * g0 + b0;
      out[(size_t)(row0 + r) * D_MODEL + c1] = (y[r][1] - mu[r]) * rstd * g1 + b1;
    }
  }
}

extern "C" void kernel_launch(void* const* d_in, const int* in_sizes, int n_in,
                              void* d_out, int out_size, void* d_ws,
                              size_t ws_size, hipStream_t stream) {
  const float* q = (const float*)d_in[0];
  const float* k = (const float*)d_in[1];
  const float* v = (const float*)d_in[2];
  const float* Wq = (const float*)d_in[3];
  const float* Wk = (const float*)d_in[4];
  const float* Wv = (const float*)d_in[5];
  const float* v_param = (const float*)d_in[6];
  const float* Wfc = (const float*)d_in[7];
  const float* gamma = (const float*)d_in[8];
  const float* beta = (const float*)d_in[9];

  float* out = (float*)d_out;                     // [B*LQ*D_MODEL]
  float* attn = out + (size_t)NB * LQ * D_MODEL;  // [B*LQ*LK]

  float* base = (float*)d_ws;
  float2* ab_g = (float2*)base;                    // [2048*64] float2
  float* ek = base + (size_t)2 * NB * LQ * DK;     // [2048*64]
  float* vp = ek + (size_t)NB * LK * DK;           // [2048*64]

  hipLaunchKernelGGL(proj_kernel, dim3(3 * 128), dim3(256), 0, stream, q, k, v,
                     Wq, Wk, Wv, v_param, ab_g, ek, vp);
  hipLaunchKernelGGL(attn_kernel, dim3(NB * LQ / RB), dim3(256), 0, stream,
                     ab_g, ek, vp, q, Wfc, gamma, beta, out, attn);
}